// Round 6
// baseline (7356.107 us; speedup 1.0000x reference)
//
#include <hip/hip_runtime.h>
#include <stdint.h>

// StackedRNN depth-3, B=16, T=2048, H=256. Inputs fp32, output fp32.
// Round 6: IN-WORKGROUP producer/consumer wave split (T16 pattern, kept
// inside one WG per stage -- R4 showed cross-WG handoff latency kills).
// 3 persistent WGs (one per depth), 512 threads = 8 waves (2/SIMD):
//   waves 0-3 (math):     acc = P[t] + W_hh @ h_{t-1} (K=256, 32 MFMA),
//                         tanh, masked out-store, h_t -> LDS ping-pong.
//   waves 4-7 (producer): P[t+1] = bias + W_ih @ inp_{t+1} (K=256, 32 MFMA)
//                         during step t (a full step of slack), inp read
//                         directly from global (2-step-deep, staged pack),
//                         P -> 16KB LDS ping-pong.
// Each wave owns 64 M-rows (wf[4][8] = 128 VGPR/lane, same as baseline).
// P handoff ordered by the existing per-step light barrier - no new sync.
// Accumulation order bias -> inp-kts -> h-kts is preserved exactly =>
// bit-identical numerics to the 2133us R3 baseline (absmax canary).
// Flags/gates/publish cadence unchanged from R3: publish every 8 steps
// (backed by full __syncthreads at (t&7)==7), upstream gate every 16.

#define TT 2048
#define HH 256

typedef _Float16 h16x8 __attribute__((ext_vector_type(8)));
typedef float f32x4 __attribute__((ext_vector_type(4)));

__device__ __forceinline__ unsigned pkrtz(float a, float b) {
  return __builtin_bit_cast(unsigned, __builtin_amdgcn_cvt_pkrtz(a, b));
}

// pack 8 fp32 -> 8 fp16 (RTZ pair-pack, same bits as baseline loader)
__device__ __forceinline__ h16x8 pack8(float4 a, float4 b) {
  uint4 u = make_uint4(pkrtz(a.x, a.y), pkrtz(a.z, a.w),
                       pkrtz(b.x, b.y), pkrtz(b.z, b.w));
  return __builtin_bit_cast(h16x8, u);
}

// tanh(x) = 1 - 2e/(1+e), e = e^{-2x} = exp2(-2*log2(e)*x).  ~1e-6 err.
__device__ __forceinline__ float tanh_fast(float x) {
  float xm = fmaxf(x, -15.0f);
  float e = __builtin_amdgcn_exp2f(xm * -2.88539008177793f);
  float r = __builtin_amdgcn_rcpf(1.0f + e);
  return __builtin_fmaf(-2.0f * e, r, 1.0f);
}

__device__ __forceinline__ void spin_ge(int* p, int need) {
  while (__hip_atomic_load(p, __ATOMIC_ACQUIRE, __HIP_MEMORY_SCOPE_AGENT) < need)
    __builtin_amdgcn_s_sleep(2);
}

// Light barrier: order LDS ops (lgkmcnt) + store-data reads (expcnt) but
// leave global loads/stores in flight (T4: no vmcnt drain in the loop).
__device__ __forceinline__ void light_barrier() {
  asm volatile("s_waitcnt expcnt(0) lgkmcnt(0)" ::: "memory");
  __builtin_amdgcn_s_barrier();
}

// h panel LDS layout (fp16, K=256): granule(16B) for (k,n): u = k>>3,
//   half-index = (u*16 + (n ^ (u&7)))*8 + (k&7)   (XOR swizzle, same as
//   baseline's verified panel; frag kt sits at rd{E,O} + kt*512).
// P panel LDS layout (fp32): [mti][wave 0..3][lane] f32x4 granules,
//   float-index = mti*1024 + mw*256 + lane*4  (contiguous b128 per lane).
__global__ __launch_bounds__(512, 2)
void stacked_rnn(const float* __restrict__ x,
                 const int* __restrict__ seq_lens,
                 const float* __restrict__ Wih,
                 const float* __restrict__ Whh,
                 const float* __restrict__ bias,
                 float* __restrict__ out,
                 int* flags) {
  const int ks = blockIdx.x;           // depth stage 0..2
  const int tid = (int)threadIdx.x;
  const int w8 = tid >> 6;             // wave 0..7
  const bool is_math = (w8 < 4);
  const int mw = w8 & 3;               // row-group: rows [64*mw, 64*mw+64)
  const int lane = tid & 63;
  const int q = lane >> 4;
  const int n = lane & 15;             // batch column

  __shared__ __align__(16) unsigned short Hsm[2][4096];  // 2 x 8KB h panels
  __shared__ __align__(16) float Psm[2][4096];           // 2 x 16KB P panels

  int* flag_up = flags + (ks - 1) * 64;
  int* flag_me = flags + ks * 64;

  // ---- persistent weight A-fragments (fp16 RNE): math=W_hh, producer=W_ih
  h16x8 wf[4][8];
  {
    const float* wsrc = (is_math ? Whh : Wih) + ks * (HH * HH);
#pragma unroll
    for (int mti = 0; mti < 4; ++mti) {
      const int fA = mw * 64 + mti * 16 + n;   // A row = lane&15
#pragma unroll
      for (int kt = 0; kt < 8; ++kt) {
        const float* src = wsrc + fA * HH + kt * 32 + q * 8;  // A k = q*8+j
        float4 a0 = ((const float4*)src)[0];
        float4 a1 = ((const float4*)src)[1];
        h16x8 f;
        f[0] = (_Float16)a0.x; f[1] = (_Float16)a0.y;
        f[2] = (_Float16)a0.z; f[3] = (_Float16)a0.w;
        f[4] = (_Float16)a1.x; f[5] = (_Float16)a1.y;
        f[6] = (_Float16)a1.z; f[7] = (_Float16)a1.w;
        wf[mti][kt] = f;
      }
    }
  }

  // ---- bias in C-layout (producer only; row = q*4+r, col = n)
  f32x4 biasv[4];
#pragma unroll
  for (int mti = 0; mti < 4; ++mti)
#pragma unroll
    for (int r = 0; r < 4; ++r)
      biasv[mti][r] = bias[ks * HH + mw * 64 + mti * 16 + q * 4 + r];

  const int sl = seq_lens[n];

  // ---- math: h-frag read offsets + h-repack write offsets
  const int rdE = (q * 16 + (n ^ q)) * 8;        // even kt: u&7 = q
  const int rdO = (q * 16 + (n ^ q ^ 4)) * 8;    // odd  kt: u&7 = q+4
  int hofs[4];
#pragma unroll
  for (int mti = 0; mti < 4; ++mti) {
    const int u = mw * 8 + mti * 2 + (q >> 1);   // row>>3
    hofs[mti] = (u * 16 + (n ^ (u & 7))) * 8 + (q & 1) * 4;
  }
  const int pofs = mw * 256 + lane * 4;          // P panel float index base

  // ---- producer: per-lane global inp base (frag kt at +kt*32, 8 floats)
  const float* ibase;
  int istr;
  if (ks == 0) { ibase = x + n * (TT * HH) + q * 8; istr = HH; }
  else { ibase = out + (n * (TT * 3) + (ks - 1)) * HH + q * 8; istr = 3 * HH; }

  // ---- prologue: zero h buf0 (h_{-1}=0); gate covers inp_0..17
  ((uint4*)&Hsm[0][0])[tid] = make_uint4(0, 0, 0, 0);
  if (ks > 0 && tid == 0) spin_ge(flag_up, 18);
  __syncthreads();

  h16x8 bfr[8];   // producer: packed inp_{t+1} B-frags (loop-carried)
  if (!is_math) {
    // P[0] = bias + W_ih @ inp_0  -> Psm[0]
    f32x4 a0 = biasv[0], a1 = biasv[1], a2 = biasv[2], a3 = biasv[3];
#pragma unroll
    for (int kt = 0; kt < 8; ++kt) {
      const float* sp = ibase + kt * 32;
      h16x8 bf = pack8(((const float4*)sp)[0], ((const float4*)(sp + 4))[0]);
      a0 = __builtin_amdgcn_mfma_f32_16x16x32_f16(wf[0][kt], bf, a0, 0, 0, 0);
      a1 = __builtin_amdgcn_mfma_f32_16x16x32_f16(wf[1][kt], bf, a1, 0, 0, 0);
      a2 = __builtin_amdgcn_mfma_f32_16x16x32_f16(wf[2][kt], bf, a2, 0, 0, 0);
      a3 = __builtin_amdgcn_mfma_f32_16x16x32_f16(wf[3][kt], bf, a3, 0, 0, 0);
    }
    *(f32x4*)&Psm[0][0 * 1024 + pofs] = a0;
    *(f32x4*)&Psm[0][1 * 1024 + pofs] = a1;
    *(f32x4*)&Psm[0][2 * 1024 + pofs] = a2;
    *(f32x4*)&Psm[0][3 * 1024 + pofs] = a3;
    // bfr = packed inp_1
#pragma unroll
    for (int kt = 0; kt < 8; ++kt) {
      const float* sp = ibase + istr + kt * 32;
      bfr[kt] = pack8(((const float4*)sp)[0], ((const float4*)(sp + 4))[0]);
    }
  }
  __syncthreads();

  float* outp = out + (n * (TT * 3) + ks) * HH + mw * 64 + q * 4;

  for (int t = 0; t < TT; ++t) {
    // ---- publish (stores drained by full barrier at end of iter t-1)
    if ((t & 7) == 0 && t > 0 && ks < 2 && tid == 0)
      __hip_atomic_store(flag_me, t, __ATOMIC_RELEASE,
                         __HIP_MEMORY_SCOPE_AGENT);
    // ---- upstream gate: iters t..t+15 load inp steps t+2..t+17
    if ((t & 15) == 0 && t > 0 && ks > 0) {
      if (tid == 0) {
        int need = t + 18;
        if (need > TT) need = TT;
        spin_ge(flag_up, need);
      }
      __syncthreads();
    }

    if (is_math) {
      // ======== math wave: acc = P[t] + W_hh @ h_{t-1} ========
      const float* Pp = &Psm[t & 1][0];
      f32x4 ac0 = *(const f32x4*)&Pp[0 * 1024 + pofs];
      f32x4 ac1 = *(const f32x4*)&Pp[1 * 1024 + pofs];
      f32x4 ac2 = *(const f32x4*)&Pp[2 * 1024 + pofs];
      f32x4 ac3 = *(const f32x4*)&Pp[3 * 1024 + pofs];
      const unsigned short* Hp = Hsm[t & 1];
#pragma unroll
      for (int kt = 0; kt < 8; ++kt) {
        const int ofs = ((kt & 1) ? rdO : rdE) + kt * 512;
        h16x8 hf = *(const h16x8*)&Hp[ofs];
        ac0 = __builtin_amdgcn_mfma_f32_16x16x32_f16(wf[0][kt], hf, ac0, 0, 0, 0);
        ac1 = __builtin_amdgcn_mfma_f32_16x16x32_f16(wf[1][kt], hf, ac1, 0, 0, 0);
        ac2 = __builtin_amdgcn_mfma_f32_16x16x32_f16(wf[2][kt], hf, ac2, 0, 0, 0);
        ac3 = __builtin_amdgcn_mfma_f32_16x16x32_f16(wf[3][kt], hf, ac3, 0, 0, 0);
      }
      const bool live = (t < sl);
      const bool wr = (t + 1 < TT);
      unsigned short* Hq = Hsm[(t & 1) ^ 1];
      f32x4 acc[4] = {ac0, ac1, ac2, ac3};
#pragma unroll
      for (int mti = 0; mti < 4; ++mti) {
        float h0 = tanh_fast(acc[mti][0]);
        float h1 = tanh_fast(acc[mti][1]);
        float h2 = tanh_fast(acc[mti][2]);
        float h3 = tanh_fast(acc[mti][3]);
        uint2 pk;
        pk.x = pkrtz(h0, h1);
        pk.y = pkrtz(h2, h3);
        float4 od;
        od.x = live ? h0 : 0.0f;
        od.y = live ? h1 : 0.0f;
        od.z = live ? h2 : 0.0f;
        od.w = live ? h3 : 0.0f;
        *(float4*)(outp + mti * 16) = od;       // fire-and-forget
        if (wr) *(uint2*)&Hq[hofs[mti]] = pk;   // h_t for next step
      }
      outp += 3 * HH;
    } else {
      // ======== producer wave: P[t+1] = bias + W_ih @ inp_{t+1} ========
      const bool more1 = (t + 1 < TT);
      const bool more2 = (t + 2 < TT);
      const float* s = ibase + (t + 2) * istr;
      float4 ra0, rb0, ra1, rb1, ra2, rb2, ra3, rb3;
      if (more2) {      // issue loads for inp_{t+2} frags 0..3
        ra0 = ((const float4*)(s + 0 * 32))[0]; rb0 = ((const float4*)(s + 0 * 32 + 4))[0];
        ra1 = ((const float4*)(s + 1 * 32))[0]; rb1 = ((const float4*)(s + 1 * 32 + 4))[0];
        ra2 = ((const float4*)(s + 2 * 32))[0]; rb2 = ((const float4*)(s + 2 * 32 + 4))[0];
        ra3 = ((const float4*)(s + 3 * 32))[0]; rb3 = ((const float4*)(s + 3 * 32 + 4))[0];
      }
      if (more1) {
        f32x4 a0 = biasv[0], a1 = biasv[1], a2 = biasv[2], a3 = biasv[3];
#pragma unroll
        for (int kt = 0; kt < 4; ++kt) {
          a0 = __builtin_amdgcn_mfma_f32_16x16x32_f16(wf[0][kt], bfr[kt], a0, 0, 0, 0);
          a1 = __builtin_amdgcn_mfma_f32_16x16x32_f16(wf[1][kt], bfr[kt], a1, 0, 0, 0);
          a2 = __builtin_amdgcn_mfma_f32_16x16x32_f16(wf[2][kt], bfr[kt], a2, 0, 0, 0);
          a3 = __builtin_amdgcn_mfma_f32_16x16x32_f16(wf[3][kt], bfr[kt], a3, 0, 0, 0);
        }
        if (more2) {    // retire frags 0..3 into bfr, reuse regs for 4..7
          bfr[0] = pack8(ra0, rb0); bfr[1] = pack8(ra1, rb1);
          bfr[2] = pack8(ra2, rb2); bfr[3] = pack8(ra3, rb3);
          ra0 = ((const float4*)(s + 4 * 32))[0]; rb0 = ((const float4*)(s + 4 * 32 + 4))[0];
          ra1 = ((const float4*)(s + 5 * 32))[0]; rb1 = ((const float4*)(s + 5 * 32 + 4))[0];
          ra2 = ((const float4*)(s + 6 * 32))[0]; rb2 = ((const float4*)(s + 6 * 32 + 4))[0];
          ra3 = ((const float4*)(s + 7 * 32))[0]; rb3 = ((const float4*)(s + 7 * 32 + 4))[0];
        }
#pragma unroll
        for (int kt = 4; kt < 8; ++kt) {
          a0 = __builtin_amdgcn_mfma_f32_16x16x32_f16(wf[0][kt], bfr[kt], a0, 0, 0, 0);
          a1 = __builtin_amdgcn_mfma_f32_16x16x32_f16(wf[1][kt], bfr[kt], a1, 0, 0, 0);
          a2 = __builtin_amdgcn_mfma_f32_16x16x32_f16(wf[2][kt], bfr[kt], a2, 0, 0, 0);
          a3 = __builtin_amdgcn_mfma_f32_16x16x32_f16(wf[3][kt], bfr[kt], a3, 0, 0, 0);
        }
        float* Pq = &Psm[(t & 1) ^ 1][0];
        *(f32x4*)&Pq[0 * 1024 + pofs] = a0;
        *(f32x4*)&Pq[1 * 1024 + pofs] = a1;
        *(f32x4*)&Pq[2 * 1024 + pofs] = a2;
        *(f32x4*)&Pq[3 * 1024 + pofs] = a3;
        if (more2) {
          bfr[4] = pack8(ra0, rb0); bfr[5] = pack8(ra1, rb1);
          bfr[6] = pack8(ra2, rb2); bfr[7] = pack8(ra3, rb3);
        }
      }
    }

    // ---- the one per-step barrier: light (no vmcnt drain) except every
    //      8th step, whose full drain backs the next publish.
    if ((t & 7) == 7) {
      __syncthreads();
    } else {
      light_barrier();
    }
  }

  if (ks < 2 && tid == 0)
    __hip_atomic_store(flag_me, TT, __ATOMIC_RELEASE, __HIP_MEMORY_SCOPE_AGENT);
}

extern "C" void kernel_launch(void* const* d_in, const int* in_sizes, int n_in,
                              void* d_out, int out_size, void* d_ws, size_t ws_size,
                              hipStream_t stream) {
  (void)in_sizes; (void)n_in; (void)out_size; (void)ws_size;
  const float* x   = (const float*)d_in[0];
  const int*   sl  = (const int*)d_in[1];
  const float* wih = (const float*)d_in[2];
  const float* whh = (const float*)d_in[3];
  const float* b   = (const float*)d_in[4];

  // zero the progress flags (ws is poisoned 0xAA before every launch)
  (void)hipMemsetAsync(d_ws, 0, 1024, stream);
  hipLaunchKernelGGL(stacked_rnn, dim3(3), dim3(512), 0, stream,
                     x, sl, wih, whh, b, (float*)d_out, (int*)d_ws);
}

// Round 7
// 2543.198 us; speedup vs baseline: 2.8925x; 2.8925x over previous
//
#include <hip/hip_runtime.h>
#include <stdint.h>

// StackedRNN depth-3, B=16, T=2048, H=256. Inputs fp32, output fp32.
// Round 7: role-split (R6) with the producer fed from LDS-staged inp
// (R6's direct-global batch-strided producer reads were a latency
// disaster: 16 pages/instr, consumed ~150cy after issue).
// 3 persistent WGs (one per depth), 512 threads = 8 waves (2/SIMD):
//   waves 0-3 (math):     acc = P[t] (LDS) + W_hh @ h_{t-1} (8 frags,
//                         32 MFMA), tanh, masked out-store, h_t -> H pong.
//   waves 4-7 (producer): P[t+1] = bias + W_ih @ inp_{t+1}, reading inp
//                         frags from the I ping-pong (staged, swizzled,
//                         baseline-verified layout), P -> P pong.
//   all 8 waves (loader): baseline chunk loader, one 32B chunk/thread,
//                         3-step-deep global prefetch; writes packed
//                         inp_{t+2} into I[t&1] during step t.
// Numerics bit-identical to the 2133us R3 baseline (same pkrtz packs,
// same RNE weight casts, accumulation order bias -> inp kts -> h kts;
// P round-trips LDS in exact fp32). absmax canary: 0.00390625.
// Sync: R3's verified cadence — light barrier (no vmcnt drain) 7/8 steps,
// full __syncthreads at (t&7)==7 backing the 8-step flag publish;
// upstream gate every 16 steps (constant 18 -> 19 for the deeper pf).

#define TT 2048
#define HH 256

typedef _Float16 h16x8 __attribute__((ext_vector_type(8)));
typedef float f32x4 __attribute__((ext_vector_type(4)));

__device__ __forceinline__ unsigned pkrtz(float a, float b) {
  return __builtin_bit_cast(unsigned, __builtin_amdgcn_cvt_pkrtz(a, b));
}

// pack 8 fp32 -> 8 fp16 halves (RTZ pair-pack, identical bits to baseline)
__device__ __forceinline__ uint4 pack8u(float4 a, float4 b) {
  return make_uint4(pkrtz(a.x, a.y), pkrtz(a.z, a.w),
                    pkrtz(b.x, b.y), pkrtz(b.z, b.w));
}

// tanh(x) = 1 - 2e/(1+e), e = e^{-2x} = exp2(-2*log2(e)*x).  ~1e-6 err.
__device__ __forceinline__ float tanh_fast(float x) {
  float xm = fmaxf(x, -15.0f);
  float e = __builtin_amdgcn_exp2f(xm * -2.88539008177793f);
  float r = __builtin_amdgcn_rcpf(1.0f + e);
  return __builtin_fmaf(-2.0f * e, r, 1.0f);
}

__device__ __forceinline__ void spin_ge(int* p, int need) {
  while (__hip_atomic_load(p, __ATOMIC_ACQUIRE, __HIP_MEMORY_SCOPE_AGENT) < need)
    __builtin_amdgcn_s_sleep(2);
}

// Light barrier: order LDS ops (lgkmcnt) + store-data reads (expcnt) but
// leave global loads/stores in flight (T4: no vmcnt drain in the loop).
__device__ __forceinline__ void light_barrier() {
  asm volatile("s_waitcnt expcnt(0) lgkmcnt(0)" ::: "memory");
  __builtin_amdgcn_s_barrier();
}

// Panel layouts (all baseline/R6-verified):
//  H/I panels (fp16, K=256): granule(16B) for (k,n): u = k>>3,
//    half-index = (u*16 + (n ^ (u&7)))*8 + (k&7); frag kt at rd{E,O}+kt*512.
//  P panels (fp32): float-index = mti*1024 + mw*256 + lane*4.
__global__ __launch_bounds__(512, 2)
void stacked_rnn(const float* __restrict__ x,
                 const int* __restrict__ seq_lens,
                 const float* __restrict__ Wih,
                 const float* __restrict__ Whh,
                 const float* __restrict__ bias,
                 float* __restrict__ out,
                 int* flags) {
  const int ks = blockIdx.x;           // depth stage 0..2
  const int tid = (int)threadIdx.x;
  const int w8 = tid >> 6;             // wave 0..7
  const bool is_math = (w8 < 4);
  const int mw = w8 & 3;               // row-group: rows [64*mw, 64*mw+64)
  const int lane = tid & 63;
  const int q = lane >> 4;
  const int n = lane & 15;             // batch column

  __shared__ __align__(16) unsigned short Hsm[2][4096];  // 2 x 8KB h panels
  __shared__ __align__(16) unsigned short Ism[2][4096];  // 2 x 8KB inp panels
  __shared__ __align__(16) float Psm[2][4096];           // 2 x 16KB P panels

  int* flag_up = flags + (ks - 1) * 64;
  int* flag_me = flags + ks * 64;

  // ---- persistent weight A-fragments (fp16 RNE): math=W_hh, producer=W_ih
  h16x8 wf[4][8];
  {
    const float* wsrc = (is_math ? Whh : Wih) + ks * (HH * HH);
#pragma unroll
    for (int mti = 0; mti < 4; ++mti) {
      const int fA = mw * 64 + mti * 16 + n;   // A row = lane&15
#pragma unroll
      for (int kt = 0; kt < 8; ++kt) {
        const float* src = wsrc + fA * HH + kt * 32 + q * 8;  // A k = q*8+j
        float4 a0 = ((const float4*)src)[0];
        float4 a1 = ((const float4*)src)[1];
        h16x8 f;
        f[0] = (_Float16)a0.x; f[1] = (_Float16)a0.y;
        f[2] = (_Float16)a0.z; f[3] = (_Float16)a0.w;
        f[4] = (_Float16)a1.x; f[5] = (_Float16)a1.y;
        f[6] = (_Float16)a1.z; f[7] = (_Float16)a1.w;
        wf[mti][kt] = f;
      }
    }
  }

  // ---- bias in C-layout (producer uses; row = q*4+r, col = n)
  f32x4 biasv[4];
#pragma unroll
  for (int mti = 0; mti < 4; ++mti)
#pragma unroll
    for (int r = 0; r < 4; ++r)
      biasv[mti][r] = bias[ks * HH + mw * 64 + mti * 16 + q * 4 + r];

  const int sl = seq_lens[n];

  // ---- B-frag read offsets (halves): frag kt at rd{E,O} + kt*512
  const int rdE = (q * 16 + (n ^ q)) * 8;        // even kt: u&7 = q
  const int rdO = (q * 16 + (n ^ q ^ 4)) * 8;    // odd  kt: u&7 = q+4
  // ---- math h-repack write offsets (uint2 = 4 halves)
  int hofs[4];
#pragma unroll
  for (int mti = 0; mti < 4; ++mti) {
    const int u = mw * 8 + mti * 2 + (q >> 1);
    hofs[mti] = (u * 16 + (n ^ (u & 7))) * 8 + (q & 1) * 4;
  }
  const int pofs = mw * 256 + lane * 4;          // P panel float index base

  // ---- loader: 512 chunks of 8 floats = {n 0..15} x {k8 0..31}, 1/thread
  const int n_l = tid >> 5;
  const int k8  = tid & 31;
  const int u_l = (k8 >> 2) * 4 + (k8 & 3);
  const int ldst = (u_l * 16 + (n_l ^ (u_l & 7))) * 8;

  const float* src_base;
  int src_stride;
  if (ks == 0) {
    src_base = x + ((n_l * TT) << 8) + (k8 << 3);
    src_stride = HH;
  } else {
    src_base = out + (((n_l * TT) * 3 + (ks - 1)) << 8) + (k8 << 3);
    src_stride = 3 * HH;
  }

  // ---- prologue: zero h buf0; gate covers inp_0..2 + window-0 pf (..18)
  ((uint4*)&Hsm[0][0])[tid] = make_uint4(0, 0, 0, 0);
  if (ks > 0 && tid == 0) spin_ge(flag_up, 19);
  __syncthreads();

  // stage inp_0 -> I[0]
  {
    float4 c0 = ((const float4*)src_base)[0];
    float4 c1 = ((const float4*)src_base)[1];
    *(uint4*)&Ism[0][ldst] = pack8u(c0, c1);
  }
  __syncthreads();

  // producer: P[0] = bias + W_ih @ inp_0 -> Psm[0]; all: stage inp_1 -> I[1],
  // load raw inp_2 -> pfB (3-step-deep pipe starts at inp_3)
  if (!is_math) {
    f32x4 a0 = biasv[0], a1 = biasv[1], a2 = biasv[2], a3 = biasv[3];
#pragma unroll
    for (int kt = 0; kt < 8; ++kt) {
      h16x8 bf = *(const h16x8*)&Ism[0][((kt & 1) ? rdO : rdE) + kt * 512];
      a0 = __builtin_amdgcn_mfma_f32_16x16x32_f16(wf[0][kt], bf, a0, 0, 0, 0);
      a1 = __builtin_amdgcn_mfma_f32_16x16x32_f16(wf[1][kt], bf, a1, 0, 0, 0);
      a2 = __builtin_amdgcn_mfma_f32_16x16x32_f16(wf[2][kt], bf, a2, 0, 0, 0);
      a3 = __builtin_amdgcn_mfma_f32_16x16x32_f16(wf[3][kt], bf, a3, 0, 0, 0);
    }
    *(f32x4*)&Psm[0][0 * 1024 + pofs] = a0;
    *(f32x4*)&Psm[0][1 * 1024 + pofs] = a1;
    *(f32x4*)&Psm[0][2 * 1024 + pofs] = a2;
    *(f32x4*)&Psm[0][3 * 1024 + pofs] = a3;
  }
  {
    float4 c0 = ((const float4*)(src_base + src_stride))[0];
    float4 c1 = ((const float4*)(src_base + src_stride))[1];
    *(uint4*)&Ism[1][ldst] = pack8u(c0, c1);
  }
  float4 pfB0 = ((const float4*)(src_base + 2 * src_stride))[0];
  float4 pfB1 = ((const float4*)(src_base + 2 * src_stride))[1];
  const float* src_pf = src_base + 3 * src_stride;
  __syncthreads();

  float* outp = out + (n * (TT * 3) + ks) * HH + mw * 64 + q * 4;

  for (int t = 0; t < TT; ++t) {
    // ---- publish (stores drained by full barrier at end of iter t-1)
    if ((t & 7) == 0 && t > 0 && ks < 2 && tid == 0)
      __hip_atomic_store(flag_me, t, __ATOMIC_RELEASE,
                         __HIP_MEMORY_SCOPE_AGENT);
    // ---- upstream gate: window t..t+15 prefetches inp up to t+18
    if ((t & 15) == 0 && t > 0 && ks > 0) {
      if (tid == 0) {
        int need = t + 19;
        if (need > TT) need = TT;
        spin_ge(flag_up, need);
      }
      __syncthreads();
    }

    // ---- issue global prefetch for inp_{t+3}
    float4 pfA0, pfA1;
    const bool more3 = (t + 3 < TT);
    if (more3) {
      pfA0 = ((const float4*)src_pf)[0];
      pfA1 = ((const float4*)src_pf)[1];
    }
    src_pf += src_stride;

    if (is_math) {
      // ======== math: acc = P[t] + W_hh @ h_{t-1}; tanh; store; h->pong ====
      const float* Pp = &Psm[t & 1][0];
      f32x4 ac0 = *(const f32x4*)&Pp[0 * 1024 + pofs];
      f32x4 ac1 = *(const f32x4*)&Pp[1 * 1024 + pofs];
      f32x4 ac2 = *(const f32x4*)&Pp[2 * 1024 + pofs];
      f32x4 ac3 = *(const f32x4*)&Pp[3 * 1024 + pofs];
      const unsigned short* Hp = Hsm[t & 1];
#pragma unroll
      for (int kt = 0; kt < 8; ++kt) {
        h16x8 hf = *(const h16x8*)&Hp[((kt & 1) ? rdO : rdE) + kt * 512];
        ac0 = __builtin_amdgcn_mfma_f32_16x16x32_f16(wf[0][kt], hf, ac0, 0, 0, 0);
        ac1 = __builtin_amdgcn_mfma_f32_16x16x32_f16(wf[1][kt], hf, ac1, 0, 0, 0);
        ac2 = __builtin_amdgcn_mfma_f32_16x16x32_f16(wf[2][kt], hf, ac2, 0, 0, 0);
        ac3 = __builtin_amdgcn_mfma_f32_16x16x32_f16(wf[3][kt], hf, ac3, 0, 0, 0);
      }
      const bool live = (t < sl);
      const bool wr = (t + 1 < TT);
      unsigned short* Hq = Hsm[(t & 1) ^ 1];
      f32x4 acc[4] = {ac0, ac1, ac2, ac3};
#pragma unroll
      for (int mti = 0; mti < 4; ++mti) {
        float h0 = tanh_fast(acc[mti][0]);
        float h1 = tanh_fast(acc[mti][1]);
        float h2 = tanh_fast(acc[mti][2]);
        float h3 = tanh_fast(acc[mti][3]);
        uint2 pk;
        pk.x = pkrtz(h0, h1);
        pk.y = pkrtz(h2, h3);
        float4 od;
        od.x = live ? h0 : 0.0f;
        od.y = live ? h1 : 0.0f;
        od.z = live ? h2 : 0.0f;
        od.w = live ? h3 : 0.0f;
        *(float4*)(outp + mti * 16) = od;       // fire-and-forget
        if (wr) *(uint2*)&Hq[hofs[mti]] = pk;   // h_t for next step
      }
      outp += 3 * HH;
    } else {
      // ======== producer: P[t+1] = bias + W_ih @ inp_{t+1} (from I LDS) ====
      if (t + 1 < TT) {
        const unsigned short* Ip = Ism[(t + 1) & 1];
        f32x4 a0 = biasv[0], a1 = biasv[1], a2 = biasv[2], a3 = biasv[3];
#pragma unroll
        for (int kt = 0; kt < 8; ++kt) {
          h16x8 bf = *(const h16x8*)&Ip[((kt & 1) ? rdO : rdE) + kt * 512];
          a0 = __builtin_amdgcn_mfma_f32_16x16x32_f16(wf[0][kt], bf, a0, 0, 0, 0);
          a1 = __builtin_amdgcn_mfma_f32_16x16x32_f16(wf[1][kt], bf, a1, 0, 0, 0);
          a2 = __builtin_amdgcn_mfma_f32_16x16x32_f16(wf[2][kt], bf, a2, 0, 0, 0);
          a3 = __builtin_amdgcn_mfma_f32_16x16x32_f16(wf[3][kt], bf, a3, 0, 0, 0);
        }
        float* Pq = &Psm[(t & 1) ^ 1][0];
        *(f32x4*)&Pq[0 * 1024 + pofs] = a0;
        *(f32x4*)&Pq[1 * 1024 + pofs] = a1;
        *(f32x4*)&Pq[2 * 1024 + pofs] = a2;
        *(f32x4*)&Pq[3 * 1024 + pofs] = a3;
      }
    }

    // ---- loader: write packed inp_{t+2} into I[t&1] (holds consumed inp_t)
    if (t + 2 < TT)
      *(uint4*)&Ism[t & 1][ldst] = pack8u(pfB0, pfB1);
    if (more3) { pfB0 = pfA0; pfB1 = pfA1; }

    // ---- the one per-step barrier: light except every 8th (backs publish)
    if ((t & 7) == 7) {
      __syncthreads();
    } else {
      light_barrier();
    }
  }

  if (ks < 2 && tid == 0)
    __hip_atomic_store(flag_me, TT, __ATOMIC_RELEASE, __HIP_MEMORY_SCOPE_AGENT);
}

extern "C" void kernel_launch(void* const* d_in, const int* in_sizes, int n_in,
                              void* d_out, int out_size, void* d_ws, size_t ws_size,
                              hipStream_t stream) {
  (void)in_sizes; (void)n_in; (void)out_size; (void)ws_size;
  const float* x   = (const float*)d_in[0];
  const int*   sl  = (const int*)d_in[1];
  const float* wih = (const float*)d_in[2];
  const float* whh = (const float*)d_in[3];
  const float* b   = (const float*)d_in[4];

  // zero the progress flags (ws is poisoned 0xAA before every launch)
  (void)hipMemsetAsync(d_ws, 0, 1024, stream);
  hipLaunchKernelGGL(stacked_rnn, dim3(3), dim3(512), 0, stream,
                     x, sl, wih, whh, b, (float*)d_out, (int*)d_ws);
}